// Round 6
// baseline (744.518 us; speedup 1.0000x reference)
//
#include <hip/hip_runtime.h>

// CNN_36644660970295: 16 steps of [wrap-pad, conv3x3 1->2ch, +b1, tanh,
// conv1x1 2->1ch, +b2, relu] on B=32, 512x512 fp32.
// Round 6: SINGLE LDS buffer (21.9 KB -> 7 WG/CU, 28 waves) with results held
// in registers across a barrier, then written in place. 256-thr blocks.

#define NN 512
#define TILE 64
#define BUFW 76                   // padded row stride (cols 0..71 live)
#define BUFH 72
#define BUFN (BUFW * BUFH)        // 5472 floats
#define WORK (70 * 9)             // 630 8-px strips per step
#define NTHR 256

typedef float f4 __attribute__((ext_vector_type(4)));

#define TWO_LOG2E 2.8853900817779268f   // 2*log2(e)

__device__ __forceinline__ float permf(int addr, float v) {
    return __builtin_bit_cast(float,
        __builtin_amdgcn_ds_bpermute(addr, __builtin_bit_cast(int, v)));
}

__global__ __launch_bounds__(NTHR, 7) void fused4(
    const float* __restrict__ in, float* __restrict__ out,
    const float* __restrict__ w1, const float* __restrict__ b1,
    const float* __restrict__ w2, const float* __restrict__ b2)
{
    __shared__ float lds[BUFN];

    const int tid = threadIdx.x;
    const int wg  = blockIdx.x;
    const int tx  = wg & 7;
    const int ty  = (wg >> 3) & 7;
    const int b   = wg >> 6;
    const float* img = in + (size_t)b * (NN * NN);
    const int base_r = ty * TILE - 4;
    const int base_c = tx * TILE - 4;

    // ---- Stage 72 rows x 72 cols (wrap halo) into 76-stride buffer ----
    #pragma unroll
    for (int k = 0; k < 6; ++k) {
        int w = tid + NTHR * k;
        if (k < 5 || w < 72 * 18) {
            int row = w / 18;
            int c4  = (w - row * 18) << 2;
            int gr  = (base_r + row) & (NN - 1);
            int gc  = (base_c + c4) & (NN - 1);
            *reinterpret_cast<f4*>(lds + row * BUFW + c4) =
                *reinterpret_cast<const f4*>(img + gr * NN + gc);
        }
    }

    // ---- Weights (uniform -> SGPRs), pre-scaled for exp2-based tanh ----
    float W1[2][3][3];
    #pragma unroll
    for (int ch = 0; ch < 2; ++ch)
        #pragma unroll
        for (int r = 0; r < 3; ++r)
            #pragma unroll
            for (int q = 0; q < 3; ++q)
                W1[ch][r][q] = w1[ch * 9 + r * 3 + q] * TWO_LOG2E;
    const float B1_0 = b1[0] * TWO_LOG2E, B1_1 = b1[1] * TWO_LOG2E;
    const float V0 = -2.0f * w2[0], V1 = -2.0f * w2[1];
    const float C2 = w2[0] + w2[1] + b2[0];

    // ---- Per-k strip geometry (reused by all 4 steps) ----
    const int lane = tid & 63;
    int  offk[3];
    bool fixL[3], fixR[3];
    #pragma unroll
    for (int k = 0; k < 3; ++k) {
        int w = tid + NTHR * k;
        int r = w / 9;                 // window top row (output row = r+1)
        int c = w - r * 9;             // strip index 0..8
        offk[k] = r * BUFW + (c << 3);
        fixL[k] = (lane == 0)  && (c != 0);
        fixR[k] = (lane == 63) && (c != 8);
    }
    const bool act2 = (tid + 2 * NTHR) < WORK;   // 118 threads on k=2
    const int aU = ((lane + 63) & 63) << 2;      // bpermute: lane-1
    const int aD = ((lane + 1)  & 63) << 2;      // bpermute: lane+1

    __syncthreads();

    // ---- 4 fused steps: compute to regs -> barrier -> write in place ----
    #pragma unroll
    for (int s = 0; s < 4; ++s) {
        float res[3][8];
        #pragma unroll
        for (int k = 0; k < 3; ++k) {
            if (k < 2 || act2) {
                const float* p = lds + offk[k];
                float wnd[3][10];
                #pragma unroll
                for (int r = 0; r < 3; ++r) {
                    f4 u = *reinterpret_cast<const f4*>(p + r * BUFW);
                    f4 v = *reinterpret_cast<const f4*>(p + r * BUFW + 4);
                    float lf = permf(aU, v.w);   // neighbor strip col c0-1
                    float rt = permf(aD, u.x);   // neighbor strip col c0+8
                    if (fixL[k]) lf = p[r * BUFW - 1];
                    if (fixR[k]) rt = p[r * BUFW + 8];
                    wnd[r][0] = lf;
                    wnd[r][1] = u.x; wnd[r][2] = u.y; wnd[r][3] = u.z; wnd[r][4] = u.w;
                    wnd[r][5] = v.x; wnd[r][6] = v.y; wnd[r][7] = v.z; wnd[r][8] = v.w;
                    wnd[r][9] = rt;
                }
                #pragma unroll
                for (int px = 0; px < 8; ++px) {
                    float a0 = B1_0, a1 = B1_1;
                    #pragma unroll
                    for (int q = 0; q < 3; ++q) {
                        a0 = fmaf(W1[0][0][q], wnd[0][px + q], a0);
                        a1 = fmaf(W1[1][0][q], wnd[0][px + q], a1);
                        a0 = fmaf(W1[0][1][q], wnd[1][px + q], a0);
                        a1 = fmaf(W1[1][1][q], wnd[1][px + q], a1);
                        a0 = fmaf(W1[0][2][q], wnd[2][px + q], a0);
                        a1 = fmaf(W1[1][2][q], wnd[2][px + q], a1);
                    }
                    float e0 = __builtin_amdgcn_exp2f(a0);
                    float e1 = __builtin_amdgcn_exp2f(a1);
                    float d0 = e0 + 1.0f, d1 = e1 + 1.0f;
                    float rr = __builtin_amdgcn_rcpf(d0 * d1);
                    float inv0 = rr * d1, inv1 = rr * d0;
                    float y = fmaf(V0, inv0, fmaf(V1, inv1, C2));
                    res[k][px] = fmaxf(y, 0.0f);
                }
            }
        }
        __syncthreads();   // all reads of this step done
        #pragma unroll
        for (int k = 0; k < 3; ++k) {
            if (k < 2 || act2) {
                float* q = lds + offk[k] + BUFW;   // output row = top+1
                *reinterpret_cast<f4*>(q) =
                    (f4){res[k][0], res[k][1], res[k][2], res[k][3]};
                *reinterpret_cast<f4*>(q + 4) =
                    (f4){res[k][4], res[k][5], res[k][6], res[k][7]};
            }
        }
        __syncthreads();   // writes visible for next step
    }

    // ---- Writeout rows/cols 4..67 ----
    float* og = out + (size_t)b * (NN * NN);
    #pragma unroll
    for (int k = 0; k < 4; ++k) {
        int w  = tid + NTHR * k;
        int rr = w >> 4;                 // 0..63
        int c4 = (w & 15) << 2;          // 0..60
        f4 v = *reinterpret_cast<const f4*>(lds + (rr + 4) * BUFW + c4 + 4);
        *reinterpret_cast<f4*>(
            og + (size_t)(ty * TILE + rr) * NN + tx * TILE + c4) = v;
    }
}

extern "C" void kernel_launch(void* const* d_in, const int* in_sizes, int n_in,
                              void* d_out, int out_size, void* d_ws, size_t ws_size,
                              hipStream_t stream) {
    const float* x  = (const float*)d_in[0];
    const float* w1 = (const float*)d_in[1];
    const float* b1 = (const float*)d_in[2];
    const float* w2 = (const float*)d_in[3];
    const float* b2 = (const float*)d_in[4];

    float* A = (float*)d_ws;    // ping
    float* B = (float*)d_out;   // pong (final group lands here)

    dim3 grid(32 * 8 * 8), block(NTHR);   // 2048 workgroups x 256

    fused4<<<grid, block, 0, stream>>>(x, A, w1, b1, w2, b2);
    fused4<<<grid, block, 0, stream>>>(A, B, w1, b1, w2, b2);
    fused4<<<grid, block, 0, stream>>>(B, A, w1, b1, w2, b2);
    fused4<<<grid, block, 0, stream>>>(A, B, w1, b1, w2, b2);
}

// Round 7
// 168.125 us; speedup vs baseline: 4.4283x; 4.4283x over previous
//
#include <hip/hip_runtime.h>

// CNN_36644660970295: 16 steps of [wrap-pad, conv3x3 1->2ch, +b1, tanh,
// conv1x1 2->1ch, +b2, relu] on B=32, 512x512 fp32.
// Round 7: rows-in-registers. Wave = full 512-col width (lane = 8-col block),
// 9 rows/wave; WG = 8 waves = 64-row band + 4+4 halo. Horizontal stencil via
// in-lane column sums + 4 ds_bpermute per row (true wrap). Vertical exchange:
// top/bottom rows through parity-double-buffered LDS, 1 barrier/step.

#define NN 512
#define NTHR 512
#define ROWS 9
#define TWO_LOG2E 2.8853900817779268f   // 2*log2(e)

typedef float f4 __attribute__((ext_vector_type(4)));

__device__ __forceinline__ float permf(int addr, float v) {
    return __builtin_bit_cast(float,
        __builtin_amdgcn_ds_bpermute(addr, __builtin_bit_cast(int, v)));
}

// tanh+conv2+relu for one pixel given both channel pre-activations (x2log2e)
#define PXOUT(A0, A1)                                                        \
    ({  float e0_ = __builtin_amdgcn_exp2f(A0);                              \
        float e1_ = __builtin_amdgcn_exp2f(A1);                              \
        float d0_ = e0_ + 1.0f, d1_ = e1_ + 1.0f;                            \
        float rc_ = __builtin_amdgcn_rcpf(d0_ * d1_);                        \
        fmaxf(fmaf(V0, rc_ * d1_, fmaf(V1, rc_ * d0_, C2)), 0.0f); })

__global__ __launch_bounds__(NTHR, 2) void fused4(
    const float* __restrict__ in, float* __restrict__ out,
    const float* __restrict__ w1p, const float* __restrict__ b1p,
    const float* __restrict__ w2p, const float* __restrict__ b2p)
{
    __shared__ float xch[2 * 8 * 2 * NN];   // [parity][wave][top/bot][col] 64KB

    const int tid  = threadIdx.x;
    const int wv   = tid >> 6;              // wave 0..7
    const int l    = tid & 63;              // lane
    const int wg   = blockIdx.x;
    const int band = wg & 7;                // 8 bands of 64 rows
    const int b    = wg >> 3;               // image
    const float* img = in + (size_t)b * (NN * NN);
    const int G  = band * 64;               // first valid global row of band
    const int c0 = l << 3;                  // col base (8 cols per lane)

    // ---- stage 9 rows/wave from global (true wrap) into registers ----
    f4 xu[ROWS], xv[ROWS];
    #pragma unroll
    for (int r = 0; r < ROWS; ++r) {
        int g = (G - 4 + ROWS * wv + r) & (NN - 1);
        const float* p = img + g * NN + c0;
        xu[r] = *reinterpret_cast<const f4*>(p);
        xv[r] = *reinterpret_cast<const f4*>(p + 4);
    }

    // ---- weights (uniform), pre-scaled for exp2-based tanh ----
    float W[2][3][3];
    #pragma unroll
    for (int ch = 0; ch < 2; ++ch)
        #pragma unroll
        for (int r = 0; r < 3; ++r)
            #pragma unroll
            for (int q = 0; q < 3; ++q)
                W[ch][r][q] = w1p[ch * 9 + r * 3 + q] * TWO_LOG2E;
    const float B10 = b1p[0] * TWO_LOG2E, B11 = b1p[1] * TWO_LOG2E;
    const float V0 = -2.0f * w2p[0], V1 = -2.0f * w2p[1];
    const float C2 = w2p[0] + w2p[1] + b2p[0];

    const int aU = ((l + 63) & 63) << 2;    // bpermute: lane-1 (wrap)
    const int aD = ((l + 1)  & 63) << 2;    // bpermute: lane+1 (wrap)

    const int P    = 8 * 2 * NN;            // parity stride (floats)
    const int topo = (wv * 2 + 0) * NN + c0;
    const int boto = (wv * 2 + 1) * NN + c0;
    const int abvo = (((wv + 7) & 7) * 2 + 1) * NN + c0;  // neighbor above's bottom
    const int belo = (((wv + 1) & 7) * 2 + 0) * NN + c0;  // neighbor below's top

    // ---- 4 fused steps ----
    #pragma unroll 1
    for (int s = 0; s < 4; ++s) {
        float* base = xch + (s & 1) * P;
        // post my current top/bottom rows
        *reinterpret_cast<f4*>(base + topo)     = xu[0];
        *reinterpret_cast<f4*>(base + topo + 4) = xv[0];
        *reinterpret_cast<f4*>(base + boto)     = xu[ROWS - 1];
        *reinterpret_cast<f4*>(base + boto + 4) = xv[ROWS - 1];
        __syncthreads();
        f4 au = *reinterpret_cast<const f4*>(base + abvo);
        f4 av = *reinterpret_cast<const f4*>(base + abvo + 4);
        f4 bu = *reinterpret_cast<const f4*>(base + belo);
        f4 bv = *reinterpret_cast<const f4*>(base + belo + 4);

        f4 pu = au, pv = av;                 // rolling prev (old values)
        #pragma unroll
        for (int r = 0; r < ROWS; ++r) {
            f4 cu = xu[r], cv = xv[r];
            f4 nu = (r == ROWS - 1) ? bu : xu[(r + 1 < ROWS) ? r + 1 : ROWS - 1];
            f4 nv = (r == ROWS - 1) ? bv : xv[(r + 1 < ROWS) ? r + 1 : ROWS - 1];

            f4 a0U, a0V, a1U, a1V;
            {   // channel 0
                f4 s0u = W[0][0][0]*pu + W[0][1][0]*cu + W[0][2][0]*nu;
                f4 s0v = W[0][0][0]*pv + W[0][1][0]*cv + W[0][2][0]*nv;
                f4 s1u = W[0][0][1]*pu + W[0][1][1]*cu + W[0][2][1]*nu + B10;
                f4 s1v = W[0][0][1]*pv + W[0][1][1]*cv + W[0][2][1]*nv + B10;
                f4 s2u = W[0][0][2]*pu + W[0][1][2]*cu + W[0][2][2]*nu;
                f4 s2v = W[0][0][2]*pv + W[0][1][2]*cv + W[0][2][2]*nv;
                float Lm = permf(aU, s0v.w);   // s0[-1] from left lane (wrap)
                float Rp = permf(aD, s2u.x);   // s2[8] from right lane (wrap)
                a0U.x = s1u.x + Lm    + s2u.y;
                a0U.y = s1u.y + s0u.x + s2u.z;
                a0U.z = s1u.z + s0u.y + s2u.w;
                a0U.w = s1u.w + s0u.z + s2v.x;
                a0V.x = s1v.x + s0u.w + s2v.y;
                a0V.y = s1v.y + s0v.x + s2v.z;
                a0V.z = s1v.z + s0v.y + s2v.w;
                a0V.w = s1v.w + s0v.z + Rp;
            }
            {   // channel 1
                f4 s0u = W[1][0][0]*pu + W[1][1][0]*cu + W[1][2][0]*nu;
                f4 s0v = W[1][0][0]*pv + W[1][1][0]*cv + W[1][2][0]*nv;
                f4 s1u = W[1][0][1]*pu + W[1][1][1]*cu + W[1][2][1]*nu + B11;
                f4 s1v = W[1][0][1]*pv + W[1][1][1]*cv + W[1][2][1]*nv + B11;
                f4 s2u = W[1][0][2]*pu + W[1][1][2]*cu + W[1][2][2]*nu;
                f4 s2v = W[1][0][2]*pv + W[1][1][2]*cv + W[1][2][2]*nv;
                float Lm = permf(aU, s0v.w);
                float Rp = permf(aD, s2u.x);
                a1U.x = s1u.x + Lm    + s2u.y;
                a1U.y = s1u.y + s0u.x + s2u.z;
                a1U.z = s1u.z + s0u.y + s2u.w;
                a1U.w = s1u.w + s0u.z + s2v.x;
                a1V.x = s1v.x + s0u.w + s2v.y;
                a1V.y = s1v.y + s0v.x + s2v.z;
                a1V.z = s1v.z + s0v.y + s2v.w;
                a1V.w = s1v.w + s0v.z + Rp;
            }
            f4 ru, rv;
            ru.x = PXOUT(a0U.x, a1U.x);
            ru.y = PXOUT(a0U.y, a1U.y);
            ru.z = PXOUT(a0U.z, a1U.z);
            ru.w = PXOUT(a0U.w, a1U.w);
            rv.x = PXOUT(a0V.x, a1V.x);
            rv.y = PXOUT(a0V.y, a1V.y);
            rv.z = PXOUT(a0V.z, a1V.z);
            rv.w = PXOUT(a0V.w, a1V.w);
            xu[r] = ru; xv[r] = rv;
            pu = cu; pv = cv;                // old row becomes prev
        }
        // no trailing barrier: next step writes the other parity slab
    }

    // ---- writeout valid band rows [4..67] ----
    float* og = out + (size_t)b * (NN * NN);
    #pragma unroll
    for (int r = 0; r < ROWS; ++r) {
        int rb = ROWS * wv + r;
        if (rb >= 4 && rb <= 67) {
            float* p = og + (size_t)(G + rb - 4) * NN + c0;
            *reinterpret_cast<f4*>(p)     = xu[r];
            *reinterpret_cast<f4*>(p + 4) = xv[r];
        }
    }
}

extern "C" void kernel_launch(void* const* d_in, const int* in_sizes, int n_in,
                              void* d_out, int out_size, void* d_ws, size_t ws_size,
                              hipStream_t stream) {
    const float* x  = (const float*)d_in[0];
    const float* w1 = (const float*)d_in[1];
    const float* b1 = (const float*)d_in[2];
    const float* w2 = (const float*)d_in[3];
    const float* b2 = (const float*)d_in[4];

    float* A = (float*)d_ws;    // ping
    float* B = (float*)d_out;   // pong (final group lands here)

    dim3 grid(256), block(NTHR);   // 32 images x 8 bands = 1 WG per CU

    fused4<<<grid, block, 0, stream>>>(x, A, w1, b1, w2, b2);
    fused4<<<grid, block, 0, stream>>>(A, B, w1, b1, w2, b2);
    fused4<<<grid, block, 0, stream>>>(B, A, w1, b1, w2, b2);
    fused4<<<grid, block, 0, stream>>>(A, B, w1, b1, w2, b2);
}